// Round 3
// baseline (1736.334 us; speedup 1.0000x reference)
//
#include <hip/hip_runtime.h>
#include <hip/hip_bf16.h>
#include <stdint.h>

#define NDIM 4096
#define PD   128
#define TS   64
#define LDP  (PD + 4)   // pad LDS row stride (132 floats) to skew banks

__device__ __forceinline__ float bf2f(unsigned int u16) {
    union { unsigned int i; float f; } v; v.i = u16 << 16; return v.f;
}
__device__ __forceinline__ unsigned short f2bf(float f) {
    union { float f; unsigned int i; } v; v.f = f;
    unsigned int x = v.i;
    return (unsigned short)((x + 0x7fffu + ((x >> 16) & 1u)) >> 16); // RNE
}

// UA[i][q] = sum_p U[i][p] * A[p][q]   (4096x128 = U(4096x128) @ A(128x128))
__global__ __launch_bounds__(128) void ua_kernel(
    const float* __restrict__ U, const float* __restrict__ A, float* __restrict__ UA)
{
    __shared__ float us[PD];
    const int i = blockIdx.x;
    const int q = threadIdx.x;
    us[q] = U[i * PD + q];
    __syncthreads();
    float acc = 0.f;
    #pragma unroll 8
    for (int p = 0; p < PD; ++p) acc += us[p] * A[p * PD + q];
    UA[i * PD + q] = acc;
}

// K = sigmoid(UA @ V^T - W) stored bf16; KT = K^T stored bf16.
__global__ __launch_bounds__(256) void buildK_kernel(
    const float* __restrict__ UA, const float* __restrict__ V,
    const float* __restrict__ W, unsigned short* __restrict__ K,
    unsigned short* __restrict__ KT)
{
    __shared__ float UAs[TS][LDP];
    __shared__ float Vs[TS][LDP];
    __shared__ float tileT[TS][TS + 1];
    const int i0 = blockIdx.y * TS, j0 = blockIdx.x * TS;
    const int t = threadIdx.x;

    for (int idx = t; idx < TS * PD / 4; idx += 256) {
        const int r = idx >> 5;          // / (PD/4 = 32)
        const int c = (idx & 31) << 2;
        *(float4*)&UAs[r][c] = *(const float4*)&UA[(size_t)(i0 + r) * PD + c];
        *(float4*)&Vs[r][c]  = *(const float4*)&V[(size_t)(j0 + r) * PD + c];
    }
    __syncthreads();

    const int tx = t & 15, ty = t >> 4;
    float acc[4][4] = {};
    for (int p = 0; p < PD; p += 4) {
        float4 a4[4], b4[4];
        #pragma unroll
        for (int ii = 0; ii < 4; ++ii) a4[ii] = *(const float4*)&UAs[ty + 16 * ii][p];
        #pragma unroll
        for (int jj = 0; jj < 4; ++jj) b4[jj] = *(const float4*)&Vs[tx + 16 * jj][p];
        #pragma unroll
        for (int ii = 0; ii < 4; ++ii)
            #pragma unroll
            for (int jj = 0; jj < 4; ++jj)
                acc[ii][jj] += a4[ii].x * b4[jj].x + a4[ii].y * b4[jj].y
                             + a4[ii].z * b4[jj].z + a4[ii].w * b4[jj].w;
    }

    #pragma unroll
    for (int ii = 0; ii < 4; ++ii) {
        const int i = ty + 16 * ii;
        #pragma unroll
        for (int jj = 0; jj < 4; ++jj) {
            const int j = tx + 16 * jj;
            const float w = W[(size_t)(i0 + i) * NDIM + (j0 + j)];
            const float k = 1.0f / (1.0f + __expf(w - acc[ii][jj])); // sigmoid(UV - W)
            K[(size_t)(i0 + i) * NDIM + (j0 + j)] = f2bf(k);
            tileT[j][i] = k;
        }
    }
    __syncthreads();
    for (int idx = t; idx < TS * TS; idx += 256) {
        const int j = idx >> 6, i = idx & 63;
        KT[(size_t)(j0 + j) * NDIM + (i0 + i)] = f2bf(tileT[j][i]);
    }
}

__global__ __launch_bounds__(256) void init_ones_kernel(float* __restrict__ v) {
    v[blockIdx.x * 256 + threadIdx.x] = 1.0f;
}

// vout[row] = num[row] / dot(M[row,:], vin)   — one wave per row, 4 rows/block
__global__ __launch_bounds__(256) void matvec_div_kernel(
    const unsigned short* __restrict__ M, const float* __restrict__ vin,
    const float* __restrict__ num, float* __restrict__ vout)
{
    const int wave = threadIdx.x >> 6;
    const int lane = threadIdx.x & 63;
    const int row  = blockIdx.x * 4 + wave;
    const unsigned short* mrow = M + (size_t)row * NDIM;
    float acc = 0.f;
    #pragma unroll
    for (int pass = 0; pass < NDIM / (64 * 8); ++pass) {   // 8 passes, 8 bf16/lane/pass
        const int j0 = (pass * 64 + lane) * 8;
        const uint4  kv = *(const uint4*)&mrow[j0];
        const float4 b0 = *(const float4*)&vin[j0];
        const float4 b1 = *(const float4*)&vin[j0 + 4];
        acc += bf2f(kv.x & 0xffffu) * b0.x;
        acc += bf2f(kv.x >> 16)     * b0.y;
        acc += bf2f(kv.y & 0xffffu) * b0.z;
        acc += bf2f(kv.y >> 16)     * b0.w;
        acc += bf2f(kv.z & 0xffffu) * b1.x;
        acc += bf2f(kv.z >> 16)     * b1.y;
        acc += bf2f(kv.w & 0xffffu) * b1.z;
        acc += bf2f(kv.w >> 16)     * b1.w;
    }
    #pragma unroll
    for (int off = 32; off > 0; off >>= 1) acc += __shfl_down(acc, off, 64);
    if (lane == 0) vout[row] = num[row] / acc;
}

// plan[i][j] = a[i] * sigmoid(UV - W) * b[j], fp32 recompute of K for accuracy
__global__ __launch_bounds__(256) void plan_kernel(
    const float* __restrict__ UA, const float* __restrict__ V,
    const float* __restrict__ W, const float* __restrict__ av,
    const float* __restrict__ bv, float* __restrict__ out)
{
    __shared__ float UAs[TS][LDP];
    __shared__ float Vs[TS][LDP];
    const int i0 = blockIdx.y * TS, j0 = blockIdx.x * TS;
    const int t = threadIdx.x;

    for (int idx = t; idx < TS * PD / 4; idx += 256) {
        const int r = idx >> 5;
        const int c = (idx & 31) << 2;
        *(float4*)&UAs[r][c] = *(const float4*)&UA[(size_t)(i0 + r) * PD + c];
        *(float4*)&Vs[r][c]  = *(const float4*)&V[(size_t)(j0 + r) * PD + c];
    }
    __syncthreads();

    const int tx = t & 15, ty = t >> 4;
    float acc[4][4] = {};
    for (int p = 0; p < PD; p += 4) {
        float4 a4[4], b4[4];
        #pragma unroll
        for (int ii = 0; ii < 4; ++ii) a4[ii] = *(const float4*)&UAs[ty + 16 * ii][p];
        #pragma unroll
        for (int jj = 0; jj < 4; ++jj) b4[jj] = *(const float4*)&Vs[tx + 16 * jj][p];
        #pragma unroll
        for (int ii = 0; ii < 4; ++ii)
            #pragma unroll
            for (int jj = 0; jj < 4; ++jj)
                acc[ii][jj] += a4[ii].x * b4[jj].x + a4[ii].y * b4[jj].y
                             + a4[ii].z * b4[jj].z + a4[ii].w * b4[jj].w;
    }

    #pragma unroll
    for (int ii = 0; ii < 4; ++ii) {
        const int i = ty + 16 * ii;
        const float ai = av[i0 + i];
        #pragma unroll
        for (int jj = 0; jj < 4; ++jj) {
            const int j = tx + 16 * jj;
            const float w = W[(size_t)(i0 + i) * NDIM + (j0 + j)];
            const float k = 1.0f / (1.0f + expf(w - acc[ii][jj]));
            out[(size_t)(i0 + i) * NDIM + (j0 + j)] = ai * k * bv[j0 + j];
        }
    }
}

extern "C" void kernel_launch(void* const* d_in, const int* in_sizes, int n_in,
                              void* d_out, int out_size, void* d_ws, size_t ws_size,
                              hipStream_t stream) {
    const float* U  = (const float*)d_in[0];
    const float* V  = (const float*)d_in[1];
    const float* W  = (const float*)d_in[2];
    const float* mu = (const float*)d_in[3];
    const float* nu = (const float*)d_in[4];
    const float* A  = (const float*)d_in[5];
    float* out = (float*)d_out;

    // K and KT (bf16, 32MB each) live in d_out (exactly out_size bytes total);
    // plan_kernel reads only UA/V/W/av/bv, so overwriting d_out at the end is safe.
    unsigned short* K  = (unsigned short*)d_out;
    unsigned short* KT = K + (size_t)NDIM * NDIM;

    // workspace: UA (2MB) | a (16KB) | b (16KB)   — ~2.1MB total
    char* ws  = (char*)d_ws;
    float* UA = (float*)ws;
    float* av = (float*)(ws + (size_t)(2u << 20));
    float* bv = av + NDIM;

    ua_kernel<<<NDIM, PD, 0, stream>>>(U, A, UA);
    dim3 gridK(NDIM / TS, NDIM / TS);
    buildK_kernel<<<gridK, 256, 0, stream>>>(UA, V, W, K, KT);
    init_ones_kernel<<<NDIM / 256, 256, 0, stream>>>(bv);

    for (int it = 0; it < 100; ++it) {
        matvec_div_kernel<<<NDIM / 4, 256, 0, stream>>>(K,  bv, mu, av);  // a = mu / (K b)
        matvec_div_kernel<<<NDIM / 4, 256, 0, stream>>>(KT, av, nu, bv);  // b = nu / (K^T a)
    }

    plan_kernel<<<gridK, 256, 0, stream>>>(UA, V, W, av, bv, out);
}

// Round 8
// 1512.422 us; speedup vs baseline: 1.1480x; 1.1480x over previous
//
#include <hip/hip_runtime.h>
#include <hip/hip_bf16.h>
#include <stdint.h>

#define NDIM 4096
#define PD   128
#define TS   64
#define KC   64          // split-K chunk
#define LDK  (KC + 4)    // LDS row stride for 64-wide chunks (68 floats: bank-skew 4)

// K = sigmoid(UA @ V^T - W): u8-quantized K and K^T (for the Sinkhorn loop),
// optional fp32 K (for the final plan). Split-K staging keeps LDS at 51.5KB
// -> 3 blocks/CU (was 84.5KB -> 1 block/CU -> 11% occupancy).
__global__ __launch_bounds__(256) void buildK_kernel(
    const float* __restrict__ UA, const float* __restrict__ V,
    const float* __restrict__ W, unsigned char* __restrict__ K8,
    unsigned char* __restrict__ KT8, float* __restrict__ K32)
{
    __shared__ float UAs[TS][LDK];
    __shared__ float Vs[TS][LDK];
    __shared__ float tileT[TS][TS + 1];
    const int i0 = blockIdx.y * TS, j0 = blockIdx.x * TS;
    const int t = threadIdx.x;
    const int tx = t & 15, ty = t >> 4;

    float acc[4][4] = {};
    for (int kc = 0; kc < PD; kc += KC) {
        // stage 64x64 fp32 chunks of UA and V (float4, coalesced 256B/16 lanes)
        for (int idx = t; idx < TS * (KC / 4); idx += 256) {
            const int r = idx >> 4;
            const int c = (idx & 15) << 2;
            *(float4*)&UAs[r][c] = *(const float4*)&UA[(size_t)(i0 + r) * PD + kc + c];
            *(float4*)&Vs[r][c]  = *(const float4*)&V[(size_t)(j0 + r) * PD + kc + c];
        }
        __syncthreads();
        for (int p = 0; p < KC; p += 4) {
            float4 a4[4], b4[4];
            #pragma unroll
            for (int ii = 0; ii < 4; ++ii) a4[ii] = *(const float4*)&UAs[ty + 16 * ii][p];
            #pragma unroll
            for (int jj = 0; jj < 4; ++jj) b4[jj] = *(const float4*)&Vs[tx + 16 * jj][p];
            #pragma unroll
            for (int ii = 0; ii < 4; ++ii)
                #pragma unroll
                for (int jj = 0; jj < 4; ++jj)
                    acc[ii][jj] += a4[ii].x * b4[jj].x + a4[ii].y * b4[jj].y
                                 + a4[ii].z * b4[jj].z + a4[ii].w * b4[jj].w;
        }
        __syncthreads();   // before next chunk overwrites the stage buffers
    }

    #pragma unroll
    for (int ii = 0; ii < 4; ++ii) {
        const int i = ty + 16 * ii;
        #pragma unroll
        for (int jj = 0; jj < 4; ++jj) {
            const int j = tx + 16 * jj;
            const float w = W[(size_t)(i0 + i) * NDIM + (j0 + j)];
            tileT[j][i] = 1.0f / (1.0f + __expf(w - acc[ii][jj])); // sigmoid(UV - W)
        }
    }
    __syncthreads();
    // pass A: K^T u8, coalesced over i
    for (int idx = t; idx < TS * TS; idx += 256) {
        const int j = idx >> 6, i = idx & 63;
        KT8[(size_t)(j0 + j) * NDIM + (i0 + i)] = (unsigned char)(tileT[j][i] * 255.f + 0.5f);
    }
    // pass B: K u8 (+ optional K fp32), coalesced over j
    for (int idx = t; idx < TS * TS; idx += 256) {
        const int i = idx >> 6, j = idx & 63;
        const float k = tileT[j][i];
        K8[(size_t)(i0 + i) * NDIM + (j0 + j)] = (unsigned char)(k * 255.f + 0.5f);
        if (K32) K32[(size_t)(i0 + i) * NDIM + (j0 + j)] = k;
    }
}

// UA[i][q] = sum_p U[i][p] * A[p][q]
__global__ __launch_bounds__(128) void ua_kernel(
    const float* __restrict__ U, const float* __restrict__ A, float* __restrict__ UA)
{
    __shared__ float us[PD];
    const int i = blockIdx.x;
    const int q = threadIdx.x;
    us[q] = U[i * PD + q];
    __syncthreads();
    float acc = 0.f;
    #pragma unroll 8
    for (int p = 0; p < PD; ++p) acc += us[p] * A[p * PD + q];
    UA[i * PD + q] = acc;
}

__global__ __launch_bounds__(256) void init_ones_kernel(float* __restrict__ v) {
    v[blockIdx.x * 256 + threadIdx.x] = 1.0f;
}

// vout[row] = scale * num[row] / dot(M_u8[row,:], vin) — one wave per row.
// u8 decode is a single v_cvt_f32_ubyte; true_dot = acc/255 -> scale=255.
__global__ __launch_bounds__(256) void matvec_u8_div_kernel(
    const unsigned char* __restrict__ M, const float* __restrict__ vin,
    const float* __restrict__ num, float* __restrict__ vout)
{
    const int wave = threadIdx.x >> 6;
    const int lane = threadIdx.x & 63;
    const int row  = blockIdx.x * 4 + wave;
    const unsigned char* mrow = M + (size_t)row * NDIM;
    float acc = 0.f;
    #pragma unroll
    for (int pass = 0; pass < NDIM / (64 * 16); ++pass) {   // 4 passes, 16 u8/lane/pass
        const int j0 = (pass * 64 + lane) * 16;
        const uint4  kv = *(const uint4*)&mrow[j0];
        const float4 b0 = *(const float4*)&vin[j0];
        const float4 b1 = *(const float4*)&vin[j0 + 4];
        const float4 b2 = *(const float4*)&vin[j0 + 8];
        const float4 b3 = *(const float4*)&vin[j0 + 12];
        acc += (float)( kv.x        & 0xffu) * b0.x;
        acc += (float)((kv.x >>  8) & 0xffu) * b0.y;
        acc += (float)((kv.x >> 16) & 0xffu) * b0.z;
        acc += (float)( kv.x >> 24         ) * b0.w;
        acc += (float)( kv.y        & 0xffu) * b1.x;
        acc += (float)((kv.y >>  8) & 0xffu) * b1.y;
        acc += (float)((kv.y >> 16) & 0xffu) * b1.z;
        acc += (float)( kv.y >> 24         ) * b1.w;
        acc += (float)( kv.z        & 0xffu) * b2.x;
        acc += (float)((kv.z >>  8) & 0xffu) * b2.y;
        acc += (float)((kv.z >> 16) & 0xffu) * b2.z;
        acc += (float)( kv.z >> 24         ) * b2.w;
        acc += (float)( kv.w        & 0xffu) * b3.x;
        acc += (float)((kv.w >>  8) & 0xffu) * b3.y;
        acc += (float)((kv.w >> 16) & 0xffu) * b3.z;
        acc += (float)( kv.w >> 24         ) * b3.w;
    }
    #pragma unroll
    for (int off = 32; off > 0; off >>= 1) acc += __shfl_down(acc, off, 64);
    if (lane == 0) vout[row] = 255.0f * num[row] / acc;
}

// fast plan: out[i][j] = a[i] * K32[i][j] * b[j]  (pure elementwise, 128MB traffic)
__global__ __launch_bounds__(256) void plan_ew_kernel(
    const float* __restrict__ K32, const float* __restrict__ av,
    const float* __restrict__ bv, float* __restrict__ out)
{
    const size_t base = ((size_t)blockIdx.x * 256 + threadIdx.x) * 4;
    const int i = (int)(base >> 12);
    const int j = (int)(base & 4095);
    const float a = av[i];
    const float4 k4 = *(const float4*)&K32[base];
    const float4 b4 = *(const float4*)&bv[j];
    float4 o;
    o.x = a * k4.x * b4.x;
    o.y = a * k4.y * b4.y;
    o.z = a * k4.z * b4.z;
    o.w = a * k4.w * b4.w;
    *(float4*)&out[base] = o;
}

// fallback plan (ws too small for K32): split-K recompute, same GEMM as buildK
__global__ __launch_bounds__(256) void plan_fb_kernel(
    const float* __restrict__ UA, const float* __restrict__ V,
    const float* __restrict__ W, const float* __restrict__ av,
    const float* __restrict__ bv, float* __restrict__ out)
{
    __shared__ float UAs[TS][LDK];
    __shared__ float Vs[TS][LDK];
    const int i0 = blockIdx.y * TS, j0 = blockIdx.x * TS;
    const int t = threadIdx.x;
    const int tx = t & 15, ty = t >> 4;

    float acc[4][4] = {};
    for (int kc = 0; kc < PD; kc += KC) {
        for (int idx = t; idx < TS * (KC / 4); idx += 256) {
            const int r = idx >> 4;
            const int c = (idx & 15) << 2;
            *(float4*)&UAs[r][c] = *(const float4*)&UA[(size_t)(i0 + r) * PD + kc + c];
            *(float4*)&Vs[r][c]  = *(const float4*)&V[(size_t)(j0 + r) * PD + kc + c];
        }
        __syncthreads();
        for (int p = 0; p < KC; p += 4) {
            float4 a4[4], b4[4];
            #pragma unroll
            for (int ii = 0; ii < 4; ++ii) a4[ii] = *(const float4*)&UAs[ty + 16 * ii][p];
            #pragma unroll
            for (int jj = 0; jj < 4; ++jj) b4[jj] = *(const float4*)&Vs[tx + 16 * jj][p];
            #pragma unroll
            for (int ii = 0; ii < 4; ++ii)
                #pragma unroll
                for (int jj = 0; jj < 4; ++jj)
                    acc[ii][jj] += a4[ii].x * b4[jj].x + a4[ii].y * b4[jj].y
                                 + a4[ii].z * b4[jj].z + a4[ii].w * b4[jj].w;
        }
        __syncthreads();
    }

    #pragma unroll
    for (int ii = 0; ii < 4; ++ii) {
        const int i = ty + 16 * ii;
        const float a = av[i0 + i];
        #pragma unroll
        for (int jj = 0; jj < 4; ++jj) {
            const int j = tx + 16 * jj;
            const float w = W[(size_t)(i0 + i) * NDIM + (j0 + j)];
            const float k = 1.0f / (1.0f + expf(w - acc[ii][jj]));
            out[(size_t)(i0 + i) * NDIM + (j0 + j)] = a * k * bv[j0 + j];
        }
    }
}

extern "C" void kernel_launch(void* const* d_in, const int* in_sizes, int n_in,
                              void* d_out, int out_size, void* d_ws, size_t ws_size,
                              hipStream_t stream) {
    const float* U  = (const float*)d_in[0];
    const float* V  = (const float*)d_in[1];
    const float* W  = (const float*)d_in[2];
    const float* mu = (const float*)d_in[3];
    const float* nu = (const float*)d_in[4];
    const float* A  = (const float*)d_in[5];
    float* out = (float*)d_out;

    // K/KT u8 (16.7MB each) live in d_out (33.5MB <= 64MB); plan overwrites at end.
    unsigned char* K8  = (unsigned char*)d_out;
    unsigned char* KT8 = K8 + (size_t)NDIM * NDIM;

    const size_t k32_bytes = (size_t)NDIM * NDIM * 4;   // 64MB
    const size_t ua_bytes  = (size_t)NDIM * PD * 4;     // 2MB
    const bool big = ws_size >= k32_bytes + ua_bytes + 3 * NDIM * 4;

    char* ws   = (char*)d_ws;
    float* K32 = big ? (float*)ws : nullptr;
    char*  p   = ws + (big ? k32_bytes : 0);
    float* UA  = (float*)p;
    float* av  = (float*)(p + ua_bytes);
    float* bv  = av + NDIM;

    ua_kernel<<<NDIM, PD, 0, stream>>>(U, A, UA);
    dim3 gridK(NDIM / TS, NDIM / TS);
    buildK_kernel<<<gridK, 256, 0, stream>>>(UA, V, W, K8, KT8, K32);
    init_ones_kernel<<<NDIM / 256, 256, 0, stream>>>(bv);

    for (int it = 0; it < 100; ++it) {
        matvec_u8_div_kernel<<<NDIM / 4, 256, 0, stream>>>(K8,  bv, mu, av);
        matvec_u8_div_kernel<<<NDIM / 4, 256, 0, stream>>>(KT8, av, nu, bv);
    }

    if (big) plan_ew_kernel<<<(NDIM / 4) * (NDIM / 256), 256, 0, stream>>>(K32, av, bv, out);
    else     plan_fb_kernel<<<gridK, 256, 0, stream>>>(UA, V, W, av, bv, out);
}